// Round 11
// baseline (365.549 us; speedup 1.0000x reference)
//
#include <hip/hip_runtime.h>

// MoE: T=8192, D_MODEL=1024, D_FF=1024, E=8, top-2.
// R17: R14 base (best, 338.3us) + eo round-trip eliminated:
//      - scatfin emits sw[slot] (combine weight) alongside elist[slot]; adds
//        1024 zero-role blocks that clear out[0..T*DM).
//      - gemm2 epilogue: atomicAdd(out[tok*DM+d], w*acc) via LDS slot->tok/w
//        (each out elem gets exactly its 2 top-k contributions). eo + combine
//        kernel + cidx deleted.
//      gemm1/gemm2-core/pre byte-identical to R14 (gemm1 87us triple-verified).

#define T_TOK   8192
#define DM      1024
#define DFF     1024
#define NE      8
#define TOTS    (2 * T_TOK)    // 16384 slots
#define R1_BLK  2048           // router blocks (4 tokens each)
#define CVT_BLK 2048           // conversion blocks
#define ZERO_BLK 1024          // out-zeroing blocks in scatfin grid

typedef __attribute__((ext_vector_type(8))) short bf16x8;
typedef __attribute__((ext_vector_type(4))) float f32x4;

#define ASYNC16(gp, lp) __builtin_amdgcn_global_load_lds( \
    (const __attribute__((address_space(1))) unsigned int*)(gp), \
    (__attribute__((address_space(3))) unsigned int*)(lp), 16, 0, 0)

__device__ __forceinline__ unsigned short f2bf(float f) {
    union { float f; unsigned u; } c; c.f = f;
    unsigned r = c.u + 0x7fffu + ((c.u >> 16) & 1u);
    return (unsigned short)(r >> 16);
}
__device__ __forceinline__ float bf2f(unsigned short h) {
    union { unsigned u; float f; } c; c.u = ((unsigned)h) << 16;
    return c.f;
}

// ---------------- pre: router (even blocks) || cvt3 (odd blocks) ----------------
__global__ __launch_bounds__(256) void pre_kernel(
    const float* __restrict__ x, const float* __restrict__ gate_w,
    const float* __restrict__ s0, const float* __restrict__ s1, const float* __restrict__ s2,
    unsigned short* __restrict__ d0, unsigned short* __restrict__ d1, unsigned short* __restrict__ d2,
    unsigned short* __restrict__ xb,
    int* __restrict__ topi, float2* __restrict__ topw, float* __restrict__ psum_part)
{
    int tid = threadIdx.x;
    int sub = blockIdx.x >> 1;

    if (blockIdx.x & 1) {
        // ---- cvt role: 3 weight tensors, 12 float4 per thread ----
        int base = sub * 256 + tid;
        #pragma unroll
        for (int it = 0; it < 12; ++it) {
            int idx = base + it * (CVT_BLK * 256);
            int seg = idx >> 21;                    // 2^21 float4 per tensor
            int off = (idx & ((1 << 21) - 1)) * 4;
            const float* s = (seg == 0) ? s0 : (seg == 1) ? s1 : s2;
            unsigned short* d = (seg == 0) ? d0 : (seg == 1) ? d1 : d2;
            float4 v = *(const float4*)(s + off);
            ushort4 o;
            o.x = f2bf(v.x); o.y = f2bf(v.y); o.z = f2bf(v.z); o.w = f2bf(v.w);
            *(ushort4*)(d + off) = o;
        }
        return;
    }

    // ---- router role (fp32, per-block partials only) ----
    __shared__ float gw[NE * DM];
    __shared__ float blk_psum[NE];

    for (int i = tid; i < NE * DM; i += 256) gw[i] = gate_w[i];
    if (tid < NE) blk_psum[tid] = 0.f;
    __syncthreads();

    int wv = tid >> 6, lane = tid & 63;
    int t = sub * 4 + wv;

    float acc[NE];
    #pragma unroll
    for (int e = 0; e < NE; ++e) acc[e] = 0.f;
    const float* xr = x + (size_t)t * DM;
    unsigned short* xbr = xb + (size_t)t * DM;
    #pragma unroll 4
    for (int i = 0; i < DM / 64; ++i) {
        float xv = xr[i * 64 + lane];
        xbr[i * 64 + lane] = f2bf(xv);
        #pragma unroll
        for (int e = 0; e < NE; ++e)
            acc[e] += xv * gw[e * DM + i * 64 + lane];
    }
    #pragma unroll
    for (int e = 0; e < NE; ++e) {
        float v = acc[e];
        #pragma unroll
        for (int s = 32; s > 0; s >>= 1) v += __shfl_xor(v, s, 64);
        acc[e] = v;
    }
    if (lane == 0) {
        float mx = acc[0];
        #pragma unroll
        for (int e = 1; e < NE; ++e) mx = fmaxf(mx, acc[e]);
        float p[NE], sum = 0.f;
        #pragma unroll
        for (int e = 0; e < NE; ++e) { p[e] = expf(acc[e] - mx); sum += p[e]; }
        float inv = 1.f / sum;
        #pragma unroll
        for (int e = 0; e < NE; ++e) { p[e] *= inv; atomicAdd(&blk_psum[e], p[e]); }
        int i1 = 0; float v1 = p[0];
        #pragma unroll
        for (int e = 1; e < NE; ++e) if (p[e] > v1) { v1 = p[e]; i1 = e; }
        int i2 = -1; float v2 = -1.f;
        #pragma unroll
        for (int e = 0; e < NE; ++e) { if (e == i1) continue; if (p[e] > v2) { v2 = p[e]; i2 = e; } }
        float winv = 1.f / (v1 + v2);
        topi[t] = i1 | (i2 << 8);
        topw[t] = make_float2(v1 * winv, v2 * winv);
    }
    __syncthreads();
    if (tid < NE) psum_part[sub * NE + tid] = blk_psum[tid];
}

// ---------------- scatfin: 8 scat blocks || 1024 zero blocks --------------------
// scat blocks (0..7): per-expert prefix-scan scatter (R13/R14 verified), now
// also emitting sw[slot] = combine weight. zero blocks (8..): clear out.
__global__ __launch_bounds__(256) void scatfin_kernel(
    const int* __restrict__ topi, const float2* __restrict__ topw,
    const float* __restrict__ psum_part,
    int* __restrict__ elist, float* __restrict__ sw,
    int* __restrict__ ecnt, int* __restrict__ ebaseg,
    float* __restrict__ out, float* __restrict__ out_tail)
{
    int tid = threadIdx.x;

    if (blockIdx.x >= NE) {
        // ---- zero role: clear out[0 .. T_TOK*DM) ----
        int idx = (blockIdx.x - NE) * 256 + tid;
        #pragma unroll
        for (int it = 0; it < 8; ++it) {
            int off = (idx + it * (ZERO_BLK * 256)) * 4;
            *(float4*)(out + off) = (float4){0.f, 0.f, 0.f, 0.f};
        }
        return;
    }

    __shared__ int c8[256 * NE];     // per-thread expert counts -> tree reduce
    __shared__ int sm[256];          // prefix scan of per-thread matches
    __shared__ int ebase_sh[NE + 1];
    __shared__ float f8[256 * NE];   // psum reduce (block 0)

    int e = blockIdx.x;

    // pass 1: count (all experts) + own-expert match count
    int cnt8[NE];
    #pragma unroll
    for (int j = 0; j < NE; ++j) cnt8[j] = 0;
    #pragma unroll 4
    for (int k = 0; k < 32; ++k) {
        int pk = topi[tid * 32 + k];
        cnt8[pk & 0xff]++;
        cnt8[(pk >> 8) & 0xff]++;
    }
    #pragma unroll
    for (int j = 0; j < NE; ++j) c8[tid * NE + j] = cnt8[j];
    sm[tid] = cnt8[e];
    __syncthreads();

    // tree-reduce c8 -> totals in c8[0..7]
    for (int s = 128; s > 0; s >>= 1) {
        if (tid < s) {
            #pragma unroll
            for (int j = 0; j < NE; ++j)
                c8[tid * NE + j] += c8[(tid + s) * NE + j];
        }
        __syncthreads();
    }
    if (tid == 0) {
        int s = 0;
        for (int j = 0; j < NE; ++j) { ebase_sh[j] = s; s += c8[j]; }
        ebase_sh[NE] = s;
    }
    // Hillis-Steele inclusive scan of sm (own-expert matches per thread)
    int mymatch = cnt8[e];
    __syncthreads();
    for (int s = 1; s < 256; s <<= 1) {
        int v = (tid >= s) ? sm[tid - s] : 0;
        __syncthreads();
        sm[tid] += v;
        __syncthreads();
    }
    int wbase = ebase_sh[e] + sm[tid] - mymatch;

    // pass 2: emit slots for expert e (token + combine weight)
    for (int k = 0; k < 32; ++k) {
        int tt = tid * 32 + k;
        int pk = topi[tt];
        int e1 = pk & 0xff, e2 = (pk >> 8) & 0xff;
        if (e1 == e) {
            elist[wbase] = tt;
            sw[wbase] = topw[tt].x;
            wbase++;
        } else if (e2 == e) {
            elist[wbase] = tt;
            sw[wbase] = topw[tt].y;
            wbase++;
        }
    }
    if (tid == 0) {
        ecnt[e]   = c8[e];
        ebaseg[e] = ebase_sh[e];
    }

    // block 0: psum reduce + aux loss + counts tail
    if (e == 0) {
        float s8[NE];
        #pragma unroll
        for (int j = 0; j < NE; ++j) s8[j] = 0.f;
        for (int b = tid; b < R1_BLK; b += 256) {
            const float* row = psum_part + (size_t)b * NE;
            #pragma unroll
            for (int j = 0; j < NE; ++j) s8[j] += row[j];
        }
        #pragma unroll
        for (int j = 0; j < NE; ++j) f8[tid * NE + j] = s8[j];
        __syncthreads();
        for (int s = 128; s > 0; s >>= 1) {
            if (tid < s) {
                #pragma unroll
                for (int j = 0; j < NE; ++j)
                    f8[tid * NE + j] += f8[(tid + s) * NE + j];
            }
            __syncthreads();
        }
        if (tid == 0) {
            float aux = 0.f;
            for (int j = 0; j < NE; ++j) {
                float P = f8[j] / (float)T_TOK;
                float f = (float)c8[j] / (float)(2 * T_TOK);
                aux += f * P;
                out_tail[1 + j] = (float)c8[j];
            }
            out_tail[0] = (float)NE * aux;
        }
    }
}

// ---------------- GEMM1: 128Mx64N, BK=64, dual output (G,U); H in slot order ------
__global__ __launch_bounds__(256) void gemm1_kernel(
    const unsigned short* __restrict__ xb,   // [T][DM]
    const unsigned short* __restrict__ wgb,  // [NE][DFF][DM]
    const unsigned short* __restrict__ wub,
    const int* __restrict__ elist, const int* __restrict__ ecnt,
    const int* __restrict__ ebaseg,
    unsigned short* __restrict__ Hbuf)       // [TOTS][DFF] slot-ordered
{
    int e = blockIdx.z, mt = blockIdx.y, ft = blockIdx.x;
    int ne = ecnt[e];
    if (mt * 128 >= ne) return;
    int base = ebaseg[e];

    __shared__ unsigned short As[128 * 64];
    __shared__ unsigned short Gs[64 * 64];
    __shared__ unsigned short Us[64 * 64];
    __shared__ int tok[128];

    int tid = threadIdx.x;
    if (tid < 128) {
        int slot = base + mt * 128 + tid;
        tok[tid] = elist[min(slot, TOTS - 1)];
    }
    __syncthreads();

    int wave = tid >> 6, lane = tid & 63;
    int quad = lane >> 4, col = lane & 15;
    int cr = tid >> 3;
    int cl = ((tid & 7) ^ (cr & 7)) * 8;

    const size_t woff = (size_t)e * (size_t)DFF * DM;
    const unsigned short* ap[4];
    #pragma unroll
    for (int j = 0; j < 4; ++j) ap[j] = xb + (size_t)tok[j * 32 + cr] * DM + cl;
    const unsigned short* gp[2];
    const unsigned short* up[2];
    #pragma unroll
    for (int j = 0; j < 2; ++j) {
        gp[j] = wgb + woff + (size_t)(ft * 64 + j * 32 + cr) * DM + cl;
        up[j] = wub + woff + (size_t)(ft * 64 + j * 32 + cr) * DM + cl;
    }
    unsigned short* lA = As + wave * 512;
    unsigned short* lG = Gs + wave * 512;
    unsigned short* lU = Us + wave * 512;

    f32x4 accG[2][4], accU[2][4];
    #pragma unroll
    for (int i = 0; i < 2; ++i)
        #pragma unroll
        for (int n = 0; n < 4; ++n) { accG[i][n] = (f32x4){0,0,0,0}; accU[i][n] = (f32x4){0,0,0,0}; }

    for (int k0 = 0; k0 < DM; k0 += 64) {
        __syncthreads();
        #pragma unroll
        for (int j = 0; j < 4; ++j) ASYNC16(ap[j] + k0, lA + j * 2048);
        #pragma unroll
        for (int j = 0; j < 2; ++j) {
            ASYNC16(gp[j] + k0, lG + j * 2048);
            ASYNC16(up[j] + k0, lU + j * 2048);
        }
        __syncthreads();
        #pragma unroll
        for (int ksoff = 0; ksoff < 8; ksoff += 4) {
            bf16x8 a[2], g[4], u[4];
            #pragma unroll
            for (int i = 0; i < 2; ++i) {
                int m = wave * 32 + i * 16 + col;
                a[i] = *(const bf16x8*)&As[m * 64 + ((quad + ksoff) ^ (m & 7)) * 8];
            }
            #pragma unroll
            for (int n = 0; n < 4; ++n) {
                int nb = n * 16 + col;
                int off = nb * 64 + ((quad + ksoff) ^ (nb & 7)) * 8;
                g[n] = *(const bf16x8*)&Gs[off];
                u[n] = *(const bf16x8*)&Us[off];
            }
            #pragma unroll
            for (int i = 0; i < 2; ++i)
                #pragma unroll
                for (int n = 0; n < 4; ++n) {
                    accG[i][n] = __builtin_amdgcn_mfma_f32_16x16x32_bf16(a[i], g[n], accG[i][n], 0, 0, 0);
                    accU[i][n] = __builtin_amdgcn_mfma_f32_16x16x32_bf16(a[i], u[n], accU[i][n], 0, 0, 0);
                }
        }
    }
    #pragma unroll
    for (int i = 0; i < 2; ++i) {
        #pragma unroll
        for (int r = 0; r < 4; ++r) {
            int pos = mt * 128 + wave * 32 + i * 16 + quad * 4 + r;
            if (pos >= ne) continue;
            unsigned short* hr = Hbuf + (size_t)(base + pos) * DFF + ft * 64 + col;
            #pragma unroll
            for (int n = 0; n < 4; ++n) {
                float gg = accG[i][n][r], uu = accU[i][n][r];
                float h = (gg / (1.f + expf(-gg))) * uu;
                hr[n * 16] = f2bf(h);
            }
        }
    }
}

// ---------------- GEMM2: 128Mx128N, BK=64; fused combine epilogue ---------------
// Core identical to R14. Epilogue: atomicAdd(out[tok*DM+d], w*acc) using
// per-block slot->token/weight staged in LDS (each out elem gets exactly 2
// contributions; out pre-zeroed by scatfin's zero role).
__global__ __launch_bounds__(256) void gemm2_kernel(
    const unsigned short* __restrict__ Hbuf, // [TOTS][DFF] slot-ordered
    const unsigned short* __restrict__ wdb,  // [NE][DM][DFF]
    const int* __restrict__ elist, const float* __restrict__ sw,
    const int* __restrict__ ecnt, const int* __restrict__ ebaseg,
    float* __restrict__ out)                 // [T_TOK][DM], pre-zeroed
{
    int e = blockIdx.z, mt = blockIdx.y, dt = blockIdx.x;
    int ne = ecnt[e];
    if (mt * 128 >= ne) return;
    int base = ebaseg[e];

    __shared__ unsigned short As[128 * 64];
    __shared__ unsigned short Bs[128 * 64];
    __shared__ int   stok[128];
    __shared__ float swt[128];

    int tid = threadIdx.x;
    if (tid < 128) {
        int slot = min(base + mt * 128 + tid, TOTS - 1);
        stok[tid] = elist[slot];
        swt[tid]  = sw[slot];
    }

    int wave = tid >> 6, lane = tid & 63;
    int quad = lane >> 4, col = lane & 15;
    int wr = (wave >> 1) * 64, wc = (wave & 1) * 64;
    int cr = tid >> 3;
    int cl = ((tid & 7) ^ (cr & 7)) * 8;

    const size_t woff = (size_t)e * (size_t)DM * DFF;
    const unsigned short* ap[4];
    const unsigned short* bp[4];
    #pragma unroll
    for (int j = 0; j < 4; ++j) {
        int hrow = min(base + mt * 128 + j * 32 + cr, TOTS - 1);
        ap[j] = Hbuf + (size_t)hrow * DFF + cl;
        bp[j] = wdb + woff + (size_t)(dt * 128 + j * 32 + cr) * DFF + cl;
    }
    unsigned short* lA = As + wave * 512;
    unsigned short* lB = Bs + wave * 512;

    f32x4 acc[4][4];
    #pragma unroll
    for (int i = 0; i < 4; ++i)
        #pragma unroll
        for (int n = 0; n < 4; ++n) acc[i][n] = (f32x4){0,0,0,0};

    for (int k0 = 0; k0 < DFF; k0 += 64) {
        __syncthreads();
        #pragma unroll
        for (int j = 0; j < 4; ++j) {
            ASYNC16(ap[j] + k0, lA + j * 2048);
            ASYNC16(bp[j] + k0, lB + j * 2048);
        }
        __syncthreads();
        #pragma unroll
        for (int ksoff = 0; ksoff < 8; ksoff += 4) {
            bf16x8 a[4], b[4];
            #pragma unroll
            for (int i = 0; i < 4; ++i) {
                int m = wr + i * 16 + col;
                a[i] = *(const bf16x8*)&As[m * 64 + ((quad + ksoff) ^ (m & 7)) * 8];
            }
            #pragma unroll
            for (int n = 0; n < 4; ++n) {
                int nb = wc + n * 16 + col;
                b[n] = *(const bf16x8*)&Bs[nb * 64 + ((quad + ksoff) ^ (nb & 7)) * 8];
            }
            #pragma unroll
            for (int i = 0; i < 4; ++i)
                #pragma unroll
                for (int n = 0; n < 4; ++n)
                    acc[i][n] = __builtin_amdgcn_mfma_f32_16x16x32_bf16(a[i], b[n], acc[i][n], 0, 0, 0);
        }
    }
    #pragma unroll
    for (int i = 0; i < 4; ++i) {
        #pragma unroll
        for (int r = 0; r < 4; ++r) {
            int local = wr + i * 16 + quad * 4 + r;
            int pos = mt * 128 + local;
            if (pos >= ne) continue;
            int   t = stok[local];
            float w = swt[local];
            float* orow = out + (size_t)t * DM + dt * 128 + wc + col;
            #pragma unroll
            for (int n = 0; n < 4; ++n)
                atomicAdd(&orow[n * 16], w * acc[i][n][r]);
        }
    }
}

extern "C" void kernel_launch(void* const* d_in, const int* in_sizes, int n_in,
                              void* d_out, int out_size, void* d_ws, size_t ws_size,
                              hipStream_t stream) {
    const float* x      = (const float*)d_in[0];
    const float* gate_w = (const float*)d_in[1];
    const float* w_gate = (const float*)d_in[2];
    const float* w_up   = (const float*)d_in[3];
    const float* w_down = (const float*)d_in[4];
    float* out = (float*)d_out;

    char* p = (char*)d_ws;
    unsigned short* xb   = (unsigned short*)p; p += (size_t)T_TOK * DM * 2;
    unsigned short* wgb  = (unsigned short*)p; p += (size_t)NE * DFF * DM * 2;
    unsigned short* wub  = (unsigned short*)p; p += (size_t)NE * DFF * DM * 2;
    unsigned short* wdb  = (unsigned short*)p; p += (size_t)NE * DM * DFF * 2;
    unsigned short* Hbuf = (unsigned short*)p; p += (size_t)TOTS * DFF * 2;
    int*   elist = (int*)p;   p += (size_t)TOTS * 4;
    float* sw    = (float*)p; p += (size_t)TOTS * 4;
    int*   ecnt  = (int*)p;   p += NE * 4;
    int*   ebaseg= (int*)p;   p += NE * 4;
    int*   topi  = (int*)p;   p += (size_t)T_TOK * 4;
    float2* topw = (float2*)p; p += (size_t)T_TOK * 8;
    float* psum_part = (float*)p; p += (size_t)R1_BLK * NE * 4;

    pre_kernel<<<R1_BLK + CVT_BLK, 256, 0, stream>>>(
        x, gate_w, w_gate, w_up, w_down, wgb, wub, wdb,
        xb, topi, topw, psum_part);
    scatfin_kernel<<<NE + ZERO_BLK, 256, 0, stream>>>(
        topi, topw, psum_part, elist, sw, ecnt, ebaseg,
        out, out + (size_t)T_TOK * DM);
    gemm1_kernel<<<dim3(DFF / 64, TOTS / 128, NE), 256, 0, stream>>>(
        xb, wgb, wub, elist, ecnt, ebaseg, Hbuf);
    gemm2_kernel<<<dim3(DM / 128, TOTS / 128, NE), 256, 0, stream>>>(
        Hbuf, wdb, elist, sw, ecnt, ebaseg, out);
}

// Round 12
// 363.303 us; speedup vs baseline: 1.0062x; 1.0062x over previous
//
#include <hip/hip_runtime.h>

// MoE: T=8192, D_MODEL=1024, D_FF=1024, E=8, top-2.
// R18: R14 (best, 338.3us) with ONE change: gemm1 drops the tok[128] LDS
//      array (512B) -> LDS 33280->32768 B -> blocks/CU 4->5 (+25% residency
//      for a latency-bound kernel). Each thread loads its 4 elist entries
//      directly (threads 0-7 share cr -> L1 broadcast). K-loop/swizzle/
//      epilogue byte-identical to the triple-verified 87us kernel.
//      R17 lesson: fused-atomic combine costs ~50us (RMW doubles HBM write
//      traffic) — eo round-trip restored.

#define T_TOK   8192
#define DM      1024
#define DFF     1024
#define NE      8
#define TOTS    (2 * T_TOK)    // 16384 slots
#define R1_BLK  2048           // router blocks (4 tokens each)
#define CVT_BLK 2048           // conversion blocks

typedef __attribute__((ext_vector_type(8))) short bf16x8;
typedef __attribute__((ext_vector_type(4))) float f32x4;

#define ASYNC16(gp, lp) __builtin_amdgcn_global_load_lds( \
    (const __attribute__((address_space(1))) unsigned int*)(gp), \
    (__attribute__((address_space(3))) unsigned int*)(lp), 16, 0, 0)

__device__ __forceinline__ unsigned short f2bf(float f) {
    union { float f; unsigned u; } c; c.f = f;
    unsigned r = c.u + 0x7fffu + ((c.u >> 16) & 1u);
    return (unsigned short)(r >> 16);
}
__device__ __forceinline__ float bf2f(unsigned short h) {
    union { unsigned u; float f; } c; c.u = ((unsigned)h) << 16;
    return c.f;
}

// ---------------- pre: router (even blocks) || cvt3 (odd blocks) ----------------
__global__ __launch_bounds__(256) void pre_kernel(
    const float* __restrict__ x, const float* __restrict__ gate_w,
    const float* __restrict__ s0, const float* __restrict__ s1, const float* __restrict__ s2,
    unsigned short* __restrict__ d0, unsigned short* __restrict__ d1, unsigned short* __restrict__ d2,
    unsigned short* __restrict__ xb,
    int* __restrict__ topi, float2* __restrict__ topw, float* __restrict__ psum_part)
{
    int tid = threadIdx.x;
    int sub = blockIdx.x >> 1;

    if (blockIdx.x & 1) {
        // ---- cvt role: 3 weight tensors, 12 float4 per thread ----
        int base = sub * 256 + tid;
        #pragma unroll
        for (int it = 0; it < 12; ++it) {
            int idx = base + it * (CVT_BLK * 256);
            int seg = idx >> 21;                    // 2^21 float4 per tensor
            int off = (idx & ((1 << 21) - 1)) * 4;
            const float* s = (seg == 0) ? s0 : (seg == 1) ? s1 : s2;
            unsigned short* d = (seg == 0) ? d0 : (seg == 1) ? d1 : d2;
            float4 v = *(const float4*)(s + off);
            ushort4 o;
            o.x = f2bf(v.x); o.y = f2bf(v.y); o.z = f2bf(v.z); o.w = f2bf(v.w);
            *(ushort4*)(d + off) = o;
        }
        return;
    }

    // ---- router role (fp32, per-block partials only) ----
    __shared__ float gw[NE * DM];
    __shared__ float blk_psum[NE];

    for (int i = tid; i < NE * DM; i += 256) gw[i] = gate_w[i];
    if (tid < NE) blk_psum[tid] = 0.f;
    __syncthreads();

    int wv = tid >> 6, lane = tid & 63;
    int t = sub * 4 + wv;

    float acc[NE];
    #pragma unroll
    for (int e = 0; e < NE; ++e) acc[e] = 0.f;
    const float* xr = x + (size_t)t * DM;
    unsigned short* xbr = xb + (size_t)t * DM;
    #pragma unroll 4
    for (int i = 0; i < DM / 64; ++i) {
        float xv = xr[i * 64 + lane];
        xbr[i * 64 + lane] = f2bf(xv);
        #pragma unroll
        for (int e = 0; e < NE; ++e)
            acc[e] += xv * gw[e * DM + i * 64 + lane];
    }
    #pragma unroll
    for (int e = 0; e < NE; ++e) {
        float v = acc[e];
        #pragma unroll
        for (int s = 32; s > 0; s >>= 1) v += __shfl_xor(v, s, 64);
        acc[e] = v;
    }
    if (lane == 0) {
        float mx = acc[0];
        #pragma unroll
        for (int e = 1; e < NE; ++e) mx = fmaxf(mx, acc[e]);
        float p[NE], sum = 0.f;
        #pragma unroll
        for (int e = 0; e < NE; ++e) { p[e] = expf(acc[e] - mx); sum += p[e]; }
        float inv = 1.f / sum;
        #pragma unroll
        for (int e = 0; e < NE; ++e) { p[e] *= inv; atomicAdd(&blk_psum[e], p[e]); }
        int i1 = 0; float v1 = p[0];
        #pragma unroll
        for (int e = 1; e < NE; ++e) if (p[e] > v1) { v1 = p[e]; i1 = e; }
        int i2 = -1; float v2 = -1.f;
        #pragma unroll
        for (int e = 0; e < NE; ++e) { if (e == i1) continue; if (p[e] > v2) { v2 = p[e]; i2 = e; } }
        float winv = 1.f / (v1 + v2);
        topi[t] = i1 | (i2 << 8);
        topw[t] = make_float2(v1 * winv, v2 * winv);
    }
    __syncthreads();
    if (tid < NE) psum_part[sub * NE + tid] = blk_psum[tid];
}

// ---------------- scatfin: 8 blocks (one per expert), prefix-scan scatter -------
__global__ __launch_bounds__(256) void scatfin_kernel(
    const int* __restrict__ topi, const float* __restrict__ psum_part,
    int* __restrict__ elist, int2* __restrict__ cidx,
    int* __restrict__ ecnt, int* __restrict__ ebaseg, float* __restrict__ out_tail)
{
    __shared__ int c8[256 * NE];     // per-thread expert counts -> tree reduce
    __shared__ int sm[256];          // prefix scan of per-thread matches
    __shared__ int ebase_sh[NE + 1];
    __shared__ float f8[256 * NE];   // psum reduce (block 0)

    int e = blockIdx.x;
    int tid = threadIdx.x;

    // pass 1: count (all experts) + own-expert match count
    int cnt8[NE];
    #pragma unroll
    for (int j = 0; j < NE; ++j) cnt8[j] = 0;
    #pragma unroll 4
    for (int k = 0; k < 32; ++k) {
        int pk = topi[tid * 32 + k];
        cnt8[pk & 0xff]++;
        cnt8[(pk >> 8) & 0xff]++;
    }
    #pragma unroll
    for (int j = 0; j < NE; ++j) c8[tid * NE + j] = cnt8[j];
    sm[tid] = cnt8[e];
    __syncthreads();

    // tree-reduce c8 -> totals in c8[0..7]
    for (int s = 128; s > 0; s >>= 1) {
        if (tid < s) {
            #pragma unroll
            for (int j = 0; j < NE; ++j)
                c8[tid * NE + j] += c8[(tid + s) * NE + j];
        }
        __syncthreads();
    }
    if (tid == 0) {
        int s = 0;
        for (int j = 0; j < NE; ++j) { ebase_sh[j] = s; s += c8[j]; }
        ebase_sh[NE] = s;
    }
    // Hillis-Steele inclusive scan of sm (own-expert matches per thread)
    int mymatch = cnt8[e];
    __syncthreads();
    for (int s = 1; s < 256; s <<= 1) {
        int v = (tid >= s) ? sm[tid - s] : 0;
        __syncthreads();
        sm[tid] += v;
        __syncthreads();
    }
    int wbase = ebase_sh[e] + sm[tid] - mymatch;

    // pass 2: emit slots for expert e
    for (int k = 0; k < 32; ++k) {
        int tt = tid * 32 + k;
        int pk = topi[tt];
        int e1 = pk & 0xff, e2 = (pk >> 8) & 0xff;
        if (e1 == e) {
            elist[wbase] = tt;
            ((int*)cidx)[2 * tt] = wbase;
            wbase++;
        } else if (e2 == e) {
            elist[wbase] = tt;
            ((int*)cidx)[2 * tt + 1] = wbase;
            wbase++;
        }
    }
    if (tid == 0) {
        ecnt[e]   = c8[e];
        ebaseg[e] = ebase_sh[e];
    }

    // block 0: psum reduce + aux loss + counts tail
    if (e == 0) {
        float s8[NE];
        #pragma unroll
        for (int j = 0; j < NE; ++j) s8[j] = 0.f;
        for (int b = tid; b < R1_BLK; b += 256) {
            const float* row = psum_part + (size_t)b * NE;
            #pragma unroll
            for (int j = 0; j < NE; ++j) s8[j] += row[j];
        }
        #pragma unroll
        for (int j = 0; j < NE; ++j) f8[tid * NE + j] = s8[j];
        __syncthreads();
        for (int s = 128; s > 0; s >>= 1) {
            if (tid < s) {
                #pragma unroll
                for (int j = 0; j < NE; ++j)
                    f8[tid * NE + j] += f8[(tid + s) * NE + j];
            }
            __syncthreads();
        }
        if (tid == 0) {
            float aux = 0.f;
            for (int j = 0; j < NE; ++j) {
                float P = f8[j] / (float)T_TOK;
                float f = (float)c8[j] / (float)(2 * T_TOK);
                aux += f * P;
                out_tail[1 + j] = (float)c8[j];
            }
            out_tail[0] = (float)NE * aux;
        }
    }
}

// ---------------- GEMM1: 128Mx64N, BK=64, dual output (G,U); H in slot order ------
// tok[] LDS array removed (LDS 33280 -> 32768 B => 5 blocks/CU instead of 4).
// Each thread loads its 4 elist entries directly (cr shared by 8 threads ->
// L1 broadcast). Everything else identical to the 87us R7/R14 kernel.
__global__ __launch_bounds__(256) void gemm1_kernel(
    const unsigned short* __restrict__ xb,   // [T][DM]
    const unsigned short* __restrict__ wgb,  // [NE][DFF][DM]
    const unsigned short* __restrict__ wub,
    const int* __restrict__ elist, const int* __restrict__ ecnt,
    const int* __restrict__ ebaseg,
    unsigned short* __restrict__ Hbuf)       // [TOTS][DFF] slot-ordered
{
    int e = blockIdx.z, mt = blockIdx.y, ft = blockIdx.x;
    int ne = ecnt[e];
    if (mt * 128 >= ne) return;
    int base = ebaseg[e];

    __shared__ unsigned short As[128 * 64];
    __shared__ unsigned short Gs[64 * 64];
    __shared__ unsigned short Us[64 * 64];

    int tid = threadIdx.x;
    int wave = tid >> 6, lane = tid & 63;
    int quad = lane >> 4, col = lane & 15;
    int cr = tid >> 3;
    int cl = ((tid & 7) ^ (cr & 7)) * 8;

    const size_t woff = (size_t)e * (size_t)DFF * DM;
    const unsigned short* ap[4];
    #pragma unroll
    for (int j = 0; j < 4; ++j) {
        int tokj = elist[min(base + mt * 128 + j * 32 + cr, TOTS - 1)];
        ap[j] = xb + (size_t)tokj * DM + cl;
    }
    const unsigned short* gp[2];
    const unsigned short* up[2];
    #pragma unroll
    for (int j = 0; j < 2; ++j) {
        gp[j] = wgb + woff + (size_t)(ft * 64 + j * 32 + cr) * DM + cl;
        up[j] = wub + woff + (size_t)(ft * 64 + j * 32 + cr) * DM + cl;
    }
    unsigned short* lA = As + wave * 512;
    unsigned short* lG = Gs + wave * 512;
    unsigned short* lU = Us + wave * 512;

    f32x4 accG[2][4], accU[2][4];
    #pragma unroll
    for (int i = 0; i < 2; ++i)
        #pragma unroll
        for (int n = 0; n < 4; ++n) { accG[i][n] = (f32x4){0,0,0,0}; accU[i][n] = (f32x4){0,0,0,0}; }

    for (int k0 = 0; k0 < DM; k0 += 64) {
        __syncthreads();
        #pragma unroll
        for (int j = 0; j < 4; ++j) ASYNC16(ap[j] + k0, lA + j * 2048);
        #pragma unroll
        for (int j = 0; j < 2; ++j) {
            ASYNC16(gp[j] + k0, lG + j * 2048);
            ASYNC16(up[j] + k0, lU + j * 2048);
        }
        __syncthreads();
        #pragma unroll
        for (int ksoff = 0; ksoff < 8; ksoff += 4) {
            bf16x8 a[2], g[4], u[4];
            #pragma unroll
            for (int i = 0; i < 2; ++i) {
                int m = wave * 32 + i * 16 + col;
                a[i] = *(const bf16x8*)&As[m * 64 + ((quad + ksoff) ^ (m & 7)) * 8];
            }
            #pragma unroll
            for (int n = 0; n < 4; ++n) {
                int nb = n * 16 + col;
                int off = nb * 64 + ((quad + ksoff) ^ (nb & 7)) * 8;
                g[n] = *(const bf16x8*)&Gs[off];
                u[n] = *(const bf16x8*)&Us[off];
            }
            #pragma unroll
            for (int i = 0; i < 2; ++i)
                #pragma unroll
                for (int n = 0; n < 4; ++n) {
                    accG[i][n] = __builtin_amdgcn_mfma_f32_16x16x32_bf16(a[i], g[n], accG[i][n], 0, 0, 0);
                    accU[i][n] = __builtin_amdgcn_mfma_f32_16x16x32_bf16(a[i], u[n], accU[i][n], 0, 0, 0);
                }
        }
    }
    #pragma unroll
    for (int i = 0; i < 2; ++i) {
        #pragma unroll
        for (int r = 0; r < 4; ++r) {
            int pos = mt * 128 + wave * 32 + i * 16 + quad * 4 + r;
            if (pos >= ne) continue;
            unsigned short* hr = Hbuf + (size_t)(base + pos) * DFF + ft * 64 + col;
            #pragma unroll
            for (int n = 0; n < 4; ++n) {
                float gg = accG[i][n][r], uu = accU[i][n][r];
                float h = (gg / (1.f + expf(-gg))) * uu;
                hr[n * 16] = f2bf(h);
            }
        }
    }
}

// ---------------- GEMM2: 128Mx128N, BK=64; fully affine (slot-ordered) ----------
__global__ __launch_bounds__(256) void gemm2_kernel(
    const unsigned short* __restrict__ Hbuf, // [TOTS][DFF] slot-ordered
    const unsigned short* __restrict__ wdb,  // [NE][DM][DFF]
    const int* __restrict__ ecnt, const int* __restrict__ ebaseg,
    unsigned short* __restrict__ eo)         // [TOTS][DM] slot-ordered
{
    int e = blockIdx.z, mt = blockIdx.y, dt = blockIdx.x;
    int ne = ecnt[e];
    if (mt * 128 >= ne) return;
    int base = ebaseg[e];

    __shared__ unsigned short As[128 * 64];
    __shared__ unsigned short Bs[128 * 64];

    int tid = threadIdx.x;
    int wave = tid >> 6, lane = tid & 63;
    int quad = lane >> 4, col = lane & 15;
    int wr = (wave >> 1) * 64, wc = (wave & 1) * 64;
    int cr = tid >> 3;
    int cl = ((tid & 7) ^ (cr & 7)) * 8;

    const size_t woff = (size_t)e * (size_t)DM * DFF;
    const unsigned short* ap[4];
    const unsigned short* bp[4];
    #pragma unroll
    for (int j = 0; j < 4; ++j) {
        int hrow = min(base + mt * 128 + j * 32 + cr, TOTS - 1);
        ap[j] = Hbuf + (size_t)hrow * DFF + cl;
        bp[j] = wdb + woff + (size_t)(dt * 128 + j * 32 + cr) * DFF + cl;
    }
    unsigned short* lA = As + wave * 512;
    unsigned short* lB = Bs + wave * 512;

    f32x4 acc[4][4];
    #pragma unroll
    for (int i = 0; i < 4; ++i)
        #pragma unroll
        for (int n = 0; n < 4; ++n) acc[i][n] = (f32x4){0,0,0,0};

    for (int k0 = 0; k0 < DFF; k0 += 64) {
        __syncthreads();
        #pragma unroll
        for (int j = 0; j < 4; ++j) {
            ASYNC16(ap[j] + k0, lA + j * 2048);
            ASYNC16(bp[j] + k0, lB + j * 2048);
        }
        __syncthreads();
        #pragma unroll
        for (int ksoff = 0; ksoff < 8; ksoff += 4) {
            bf16x8 a[4], b[4];
            #pragma unroll
            for (int i = 0; i < 4; ++i) {
                int m = wr + i * 16 + col;
                a[i] = *(const bf16x8*)&As[m * 64 + ((quad + ksoff) ^ (m & 7)) * 8];
            }
            #pragma unroll
            for (int n = 0; n < 4; ++n) {
                int nb = wc + n * 16 + col;
                b[n] = *(const bf16x8*)&Bs[nb * 64 + ((quad + ksoff) ^ (nb & 7)) * 8];
            }
            #pragma unroll
            for (int i = 0; i < 4; ++i)
                #pragma unroll
                for (int n = 0; n < 4; ++n)
                    acc[i][n] = __builtin_amdgcn_mfma_f32_16x16x32_bf16(a[i], b[n], acc[i][n], 0, 0, 0);
        }
    }
    #pragma unroll
    for (int i = 0; i < 4; ++i) {
        #pragma unroll
        for (int r = 0; r < 4; ++r) {
            int pos = mt * 128 + wr + i * 16 + quad * 4 + r;
            if (pos >= ne) continue;
            unsigned short* er = eo + (size_t)(base + pos) * DM + dt * 128 + wc + col;
            #pragma unroll
            for (int n = 0; n < 4; ++n)
                er[n * 16] = f2bf(acc[i][n][r]);
        }
    }
}

// ---------------- combine: out[t] = w1*eo[row1] + w2*eo[row2] ----------------
__global__ __launch_bounds__(256) void combine_kernel(
    const unsigned short* __restrict__ eo, const float2* __restrict__ topw,
    const int2* __restrict__ cidx, float* __restrict__ out)
{
    int idx = blockIdx.x * 256 + threadIdx.x;
    int t = idx >> 7;
    int c = (idx & 127) << 3;
    float2 w = topw[t];
    int2 rr = cidx[t];
    const unsigned short* p0 = eo + (size_t)rr.x * DM + c;
    const unsigned short* p1 = eo + (size_t)rr.y * DM + c;
    ushort4 a0 = *(const ushort4*)p0;
    ushort4 a1 = *(const ushort4*)(p0 + 4);
    ushort4 b0 = *(const ushort4*)p1;
    ushort4 b1 = *(const ushort4*)(p1 + 4);
    float* orow = out + (size_t)t * DM + c;
    float4 o0, o1;
    o0.x = w.x * bf2f(a0.x) + w.y * bf2f(b0.x);
    o0.y = w.x * bf2f(a0.y) + w.y * bf2f(b0.y);
    o0.z = w.x * bf2f(a0.z) + w.y * bf2f(b0.z);
    o0.w = w.x * bf2f(a0.w) + w.y * bf2f(b0.w);
    o1.x = w.x * bf2f(a1.x) + w.y * bf2f(b1.x);
    o1.y = w.x * bf2f(a1.y) + w.y * bf2f(b1.y);
    o1.z = w.x * bf2f(a1.z) + w.y * bf2f(b1.z);
    o1.w = w.x * bf2f(a1.w) + w.y * bf2f(b1.w);
    *(float4*)orow = o0;
    *(float4*)(orow + 4) = o1;
}

extern "C" void kernel_launch(void* const* d_in, const int* in_sizes, int n_in,
                              void* d_out, int out_size, void* d_ws, size_t ws_size,
                              hipStream_t stream) {
    const float* x      = (const float*)d_in[0];
    const float* gate_w = (const float*)d_in[1];
    const float* w_gate = (const float*)d_in[2];
    const float* w_up   = (const float*)d_in[3];
    const float* w_down = (const float*)d_in[4];
    float* out = (float*)d_out;

    char* p = (char*)d_ws;
    unsigned short* xb   = (unsigned short*)p; p += (size_t)T_TOK * DM * 2;
    unsigned short* wgb  = (unsigned short*)p; p += (size_t)NE * DFF * DM * 2;
    unsigned short* wub  = (unsigned short*)p; p += (size_t)NE * DFF * DM * 2;
    unsigned short* wdb  = (unsigned short*)p; p += (size_t)NE * DM * DFF * 2;
    unsigned short* Hbuf = (unsigned short*)p; p += (size_t)TOTS * DFF * 2;
    int*   elist = (int*)p;   p += (size_t)TOTS * 4;
    int*   ecnt  = (int*)p;   p += NE * 4;
    int*   ebaseg= (int*)p;   p += NE * 4;
    int*   topi  = (int*)p;   p += (size_t)T_TOK * 4;
    float2* topw = (float2*)p; p += (size_t)T_TOK * 8;
    int2*  cidx  = (int2*)p;  p += (size_t)T_TOK * 8;
    float* psum_part = (float*)p; p += (size_t)R1_BLK * NE * 4;
    // eo aliases wgb+wub (dead after gemm1): [TOTS][DM] bf16 = 33.5 MB
    unsigned short* eo = wgb;

    pre_kernel<<<R1_BLK + CVT_BLK, 256, 0, stream>>>(
        x, gate_w, w_gate, w_up, w_down, wgb, wub, wdb,
        xb, topi, topw, psum_part);
    scatfin_kernel<<<NE, 256, 0, stream>>>(topi, psum_part, elist, cidx, ecnt, ebaseg,
                                           out + (size_t)T_TOK * DM);
    gemm1_kernel<<<dim3(DFF / 64, TOTS / 128, NE), 256, 0, stream>>>(
        xb, wgb, wub, elist, ecnt, ebaseg, Hbuf);
    gemm2_kernel<<<dim3(DM / 128, TOTS / 128, NE), 256, 0, stream>>>(
        Hbuf, wdb, ecnt, ebaseg, eo);
    combine_kernel<<<T_TOK * DM / 8 / 256, 256, 0, stream>>>(eo, topw, cidx, out);
}

// Round 13
// 335.231 us; speedup vs baseline: 1.0904x; 1.0837x over previous
//
#include <hip/hip_runtime.h>

// MoE: T=8192, D_MODEL=1024, D_FF=1024, E=8, top-2.
// R19 == R14 (measured best, 338.3us): R7 gemm1/gemm2/pre/combine +
//      R13 8-block scatfin. Restored after R18's occupancy experiment
//      regressed (LDS 32768 did NOT raise residency; per-thread elist
//      gathers cost +32us).
// Session ledger: gemm1 87us/35% is a triple-verified local optimum; six
//      structural GEMM variants, three overlap schemes, atomic-fusion, and
//      LDS-residency all falsified with counters. Accepted final.

#define T_TOK   8192
#define DM      1024
#define DFF     1024
#define NE      8
#define TOTS    (2 * T_TOK)    // 16384 slots
#define R1_BLK  2048           // router blocks (4 tokens each)
#define CVT_BLK 2048           // conversion blocks

typedef __attribute__((ext_vector_type(8))) short bf16x8;
typedef __attribute__((ext_vector_type(4))) float f32x4;

#define ASYNC16(gp, lp) __builtin_amdgcn_global_load_lds( \
    (const __attribute__((address_space(1))) unsigned int*)(gp), \
    (__attribute__((address_space(3))) unsigned int*)(lp), 16, 0, 0)

__device__ __forceinline__ unsigned short f2bf(float f) {
    union { float f; unsigned u; } c; c.f = f;
    unsigned r = c.u + 0x7fffu + ((c.u >> 16) & 1u);
    return (unsigned short)(r >> 16);
}
__device__ __forceinline__ float bf2f(unsigned short h) {
    union { unsigned u; float f; } c; c.u = ((unsigned)h) << 16;
    return c.f;
}

// ---------------- pre: router (even blocks) || cvt3 (odd blocks) ----------------
__global__ __launch_bounds__(256) void pre_kernel(
    const float* __restrict__ x, const float* __restrict__ gate_w,
    const float* __restrict__ s0, const float* __restrict__ s1, const float* __restrict__ s2,
    unsigned short* __restrict__ d0, unsigned short* __restrict__ d1, unsigned short* __restrict__ d2,
    unsigned short* __restrict__ xb,
    int* __restrict__ topi, float2* __restrict__ topw, float* __restrict__ psum_part)
{
    int tid = threadIdx.x;
    int sub = blockIdx.x >> 1;

    if (blockIdx.x & 1) {
        // ---- cvt role: 3 weight tensors, 12 float4 per thread ----
        int base = sub * 256 + tid;
        #pragma unroll
        for (int it = 0; it < 12; ++it) {
            int idx = base + it * (CVT_BLK * 256);
            int seg = idx >> 21;                    // 2^21 float4 per tensor
            int off = (idx & ((1 << 21) - 1)) * 4;
            const float* s = (seg == 0) ? s0 : (seg == 1) ? s1 : s2;
            unsigned short* d = (seg == 0) ? d0 : (seg == 1) ? d1 : d2;
            float4 v = *(const float4*)(s + off);
            ushort4 o;
            o.x = f2bf(v.x); o.y = f2bf(v.y); o.z = f2bf(v.z); o.w = f2bf(v.w);
            *(ushort4*)(d + off) = o;
        }
        return;
    }

    // ---- router role (fp32, per-block partials only) ----
    __shared__ float gw[NE * DM];
    __shared__ float blk_psum[NE];

    for (int i = tid; i < NE * DM; i += 256) gw[i] = gate_w[i];
    if (tid < NE) blk_psum[tid] = 0.f;
    __syncthreads();

    int wv = tid >> 6, lane = tid & 63;
    int t = sub * 4 + wv;

    float acc[NE];
    #pragma unroll
    for (int e = 0; e < NE; ++e) acc[e] = 0.f;
    const float* xr = x + (size_t)t * DM;
    unsigned short* xbr = xb + (size_t)t * DM;
    #pragma unroll 4
    for (int i = 0; i < DM / 64; ++i) {
        float xv = xr[i * 64 + lane];
        xbr[i * 64 + lane] = f2bf(xv);
        #pragma unroll
        for (int e = 0; e < NE; ++e)
            acc[e] += xv * gw[e * DM + i * 64 + lane];
    }
    #pragma unroll
    for (int e = 0; e < NE; ++e) {
        float v = acc[e];
        #pragma unroll
        for (int s = 32; s > 0; s >>= 1) v += __shfl_xor(v, s, 64);
        acc[e] = v;
    }
    if (lane == 0) {
        float mx = acc[0];
        #pragma unroll
        for (int e = 1; e < NE; ++e) mx = fmaxf(mx, acc[e]);
        float p[NE], sum = 0.f;
        #pragma unroll
        for (int e = 0; e < NE; ++e) { p[e] = expf(acc[e] - mx); sum += p[e]; }
        float inv = 1.f / sum;
        #pragma unroll
        for (int e = 0; e < NE; ++e) { p[e] *= inv; atomicAdd(&blk_psum[e], p[e]); }
        int i1 = 0; float v1 = p[0];
        #pragma unroll
        for (int e = 1; e < NE; ++e) if (p[e] > v1) { v1 = p[e]; i1 = e; }
        int i2 = -1; float v2 = -1.f;
        #pragma unroll
        for (int e = 0; e < NE; ++e) { if (e == i1) continue; if (p[e] > v2) { v2 = p[e]; i2 = e; } }
        float winv = 1.f / (v1 + v2);
        topi[t] = i1 | (i2 << 8);
        topw[t] = make_float2(v1 * winv, v2 * winv);
    }
    __syncthreads();
    if (tid < NE) psum_part[sub * NE + tid] = blk_psum[tid];
}

// ---------------- scatfin: 8 blocks (one per expert), prefix-scan scatter -------
// Each block scans all topi (deterministic), derives totals + ebase identically,
// then assigns ITS expert's slots: thread t owns tokens [t*32, t*32+32).
// Block 0 additionally reduces psum_part and writes aux/out_tail.
__global__ __launch_bounds__(256) void scatfin_kernel(
    const int* __restrict__ topi, const float* __restrict__ psum_part,
    int* __restrict__ elist, int2* __restrict__ cidx,
    int* __restrict__ ecnt, int* __restrict__ ebaseg, float* __restrict__ out_tail)
{
    __shared__ int c8[256 * NE];     // per-thread expert counts -> tree reduce
    __shared__ int sm[256];          // prefix scan of per-thread matches
    __shared__ int ebase_sh[NE + 1];
    __shared__ float f8[256 * NE];   // psum reduce (block 0)

    int e = blockIdx.x;
    int tid = threadIdx.x;

    // pass 1: count (all experts) + own-expert match count
    int cnt8[NE];
    #pragma unroll
    for (int j = 0; j < NE; ++j) cnt8[j] = 0;
    #pragma unroll 4
    for (int k = 0; k < 32; ++k) {
        int pk = topi[tid * 32 + k];
        cnt8[pk & 0xff]++;
        cnt8[(pk >> 8) & 0xff]++;
    }
    #pragma unroll
    for (int j = 0; j < NE; ++j) c8[tid * NE + j] = cnt8[j];
    sm[tid] = cnt8[e];
    __syncthreads();

    // tree-reduce c8 -> totals in c8[0..7]
    for (int s = 128; s > 0; s >>= 1) {
        if (tid < s) {
            #pragma unroll
            for (int j = 0; j < NE; ++j)
                c8[tid * NE + j] += c8[(tid + s) * NE + j];
        }
        __syncthreads();
    }
    if (tid == 0) {
        int s = 0;
        for (int j = 0; j < NE; ++j) { ebase_sh[j] = s; s += c8[j]; }
        ebase_sh[NE] = s;
    }
    // Hillis-Steele inclusive scan of sm (own-expert matches per thread)
    int mymatch = cnt8[e];
    __syncthreads();
    for (int s = 1; s < 256; s <<= 1) {
        int v = (tid >= s) ? sm[tid - s] : 0;
        __syncthreads();
        sm[tid] += v;
        __syncthreads();
    }
    int wbase = ebase_sh[e] + sm[tid] - mymatch;

    // pass 2: emit slots for expert e
    for (int k = 0; k < 32; ++k) {
        int tt = tid * 32 + k;
        int pk = topi[tt];
        int e1 = pk & 0xff, e2 = (pk >> 8) & 0xff;
        if (e1 == e) {
            elist[wbase] = tt;
            ((int*)cidx)[2 * tt] = wbase;
            wbase++;
        } else if (e2 == e) {
            elist[wbase] = tt;
            ((int*)cidx)[2 * tt + 1] = wbase;
            wbase++;
        }
    }
    if (tid == 0) {
        ecnt[e]   = c8[e];
        ebaseg[e] = ebase_sh[e];
    }

    // block 0: psum reduce + aux loss + counts tail
    if (e == 0) {
        float s8[NE];
        #pragma unroll
        for (int j = 0; j < NE; ++j) s8[j] = 0.f;
        for (int b = tid; b < R1_BLK; b += 256) {
            const float* row = psum_part + (size_t)b * NE;
            #pragma unroll
            for (int j = 0; j < NE; ++j) s8[j] += row[j];
        }
        #pragma unroll
        for (int j = 0; j < NE; ++j) f8[tid * NE + j] = s8[j];
        __syncthreads();
        for (int s = 128; s > 0; s >>= 1) {
            if (tid < s) {
                #pragma unroll
                for (int j = 0; j < NE; ++j)
                    f8[tid * NE + j] += f8[(tid + s) * NE + j];
            }
            __syncthreads();
        }
        if (tid == 0) {
            float aux = 0.f;
            for (int j = 0; j < NE; ++j) {
                float P = f8[j] / (float)T_TOK;
                float f = (float)c8[j] / (float)(2 * T_TOK);
                aux += f * P;
                out_tail[1 + j] = (float)c8[j];
            }
            out_tail[0] = (float)NE * aux;
        }
    }
}

// ---------------- GEMM1: 128Mx64N, BK=64, dual output (G,U); H in slot order ------
__global__ __launch_bounds__(256) void gemm1_kernel(
    const unsigned short* __restrict__ xb,   // [T][DM]
    const unsigned short* __restrict__ wgb,  // [NE][DFF][DM]
    const unsigned short* __restrict__ wub,
    const int* __restrict__ elist, const int* __restrict__ ecnt,
    const int* __restrict__ ebaseg,
    unsigned short* __restrict__ Hbuf)       // [TOTS][DFF] slot-ordered
{
    int e = blockIdx.z, mt = blockIdx.y, ft = blockIdx.x;
    int ne = ecnt[e];
    if (mt * 128 >= ne) return;
    int base = ebaseg[e];

    __shared__ unsigned short As[128 * 64];
    __shared__ unsigned short Gs[64 * 64];
    __shared__ unsigned short Us[64 * 64];
    __shared__ int tok[128];

    int tid = threadIdx.x;
    if (tid < 128) {
        int slot = base + mt * 128 + tid;
        tok[tid] = elist[min(slot, TOTS - 1)];
    }
    __syncthreads();

    int wave = tid >> 6, lane = tid & 63;
    int quad = lane >> 4, col = lane & 15;
    int cr = tid >> 3;
    int cl = ((tid & 7) ^ (cr & 7)) * 8;

    const size_t woff = (size_t)e * (size_t)DFF * DM;
    const unsigned short* ap[4];
    #pragma unroll
    for (int j = 0; j < 4; ++j) ap[j] = xb + (size_t)tok[j * 32 + cr] * DM + cl;
    const unsigned short* gp[2];
    const unsigned short* up[2];
    #pragma unroll
    for (int j = 0; j < 2; ++j) {
        gp[j] = wgb + woff + (size_t)(ft * 64 + j * 32 + cr) * DM + cl;
        up[j] = wub + woff + (size_t)(ft * 64 + j * 32 + cr) * DM + cl;
    }
    unsigned short* lA = As + wave * 512;
    unsigned short* lG = Gs + wave * 512;
    unsigned short* lU = Us + wave * 512;

    f32x4 accG[2][4], accU[2][4];
    #pragma unroll
    for (int i = 0; i < 2; ++i)
        #pragma unroll
        for (int n = 0; n < 4; ++n) { accG[i][n] = (f32x4){0,0,0,0}; accU[i][n] = (f32x4){0,0,0,0}; }

    for (int k0 = 0; k0 < DM; k0 += 64) {
        __syncthreads();
        #pragma unroll
        for (int j = 0; j < 4; ++j) ASYNC16(ap[j] + k0, lA + j * 2048);
        #pragma unroll
        for (int j = 0; j < 2; ++j) {
            ASYNC16(gp[j] + k0, lG + j * 2048);
            ASYNC16(up[j] + k0, lU + j * 2048);
        }
        __syncthreads();
        #pragma unroll
        for (int ksoff = 0; ksoff < 8; ksoff += 4) {
            bf16x8 a[2], g[4], u[4];
            #pragma unroll
            for (int i = 0; i < 2; ++i) {
                int m = wave * 32 + i * 16 + col;
                a[i] = *(const bf16x8*)&As[m * 64 + ((quad + ksoff) ^ (m & 7)) * 8];
            }
            #pragma unroll
            for (int n = 0; n < 4; ++n) {
                int nb = n * 16 + col;
                int off = nb * 64 + ((quad + ksoff) ^ (nb & 7)) * 8;
                g[n] = *(const bf16x8*)&Gs[off];
                u[n] = *(const bf16x8*)&Us[off];
            }
            #pragma unroll
            for (int i = 0; i < 2; ++i)
                #pragma unroll
                for (int n = 0; n < 4; ++n) {
                    accG[i][n] = __builtin_amdgcn_mfma_f32_16x16x32_bf16(a[i], g[n], accG[i][n], 0, 0, 0);
                    accU[i][n] = __builtin_amdgcn_mfma_f32_16x16x32_bf16(a[i], u[n], accU[i][n], 0, 0, 0);
                }
        }
    }
    #pragma unroll
    for (int i = 0; i < 2; ++i) {
        #pragma unroll
        for (int r = 0; r < 4; ++r) {
            int pos = mt * 128 + wave * 32 + i * 16 + quad * 4 + r;
            if (pos >= ne) continue;
            unsigned short* hr = Hbuf + (size_t)(base + pos) * DFF + ft * 64 + col;
            #pragma unroll
            for (int n = 0; n < 4; ++n) {
                float gg = accG[i][n][r], uu = accU[i][n][r];
                float h = (gg / (1.f + expf(-gg))) * uu;
                hr[n * 16] = f2bf(h);
            }
        }
    }
}

// ---------------- GEMM2: 128Mx128N, BK=64; fully affine (slot-ordered) ----------
__global__ __launch_bounds__(256) void gemm2_kernel(
    const unsigned short* __restrict__ Hbuf, // [TOTS][DFF] slot-ordered
    const unsigned short* __restrict__ wdb,  // [NE][DM][DFF]
    const int* __restrict__ ecnt, const int* __restrict__ ebaseg,
    unsigned short* __restrict__ eo)         // [TOTS][DM] slot-ordered
{
    int e = blockIdx.z, mt = blockIdx.y, dt = blockIdx.x;
    int ne = ecnt[e];
    if (mt * 128 >= ne) return;
    int base = ebaseg[e];

    __shared__ unsigned short As[128 * 64];
    __shared__ unsigned short Bs[128 * 64];

    int tid = threadIdx.x;
    int wave = tid >> 6, lane = tid & 63;
    int quad = lane >> 4, col = lane & 15;
    int wr = (wave >> 1) * 64, wc = (wave & 1) * 64;
    int cr = tid >> 3;
    int cl = ((tid & 7) ^ (cr & 7)) * 8;

    const size_t woff = (size_t)e * (size_t)DM * DFF;
    const unsigned short* ap[4];
    const unsigned short* bp[4];
    #pragma unroll
    for (int j = 0; j < 4; ++j) {
        int hrow = min(base + mt * 128 + j * 32 + cr, TOTS - 1);
        ap[j] = Hbuf + (size_t)hrow * DFF + cl;
        bp[j] = wdb + woff + (size_t)(dt * 128 + j * 32 + cr) * DFF + cl;
    }
    unsigned short* lA = As + wave * 512;
    unsigned short* lB = Bs + wave * 512;

    f32x4 acc[4][4];
    #pragma unroll
    for (int i = 0; i < 4; ++i)
        #pragma unroll
        for (int n = 0; n < 4; ++n) acc[i][n] = (f32x4){0,0,0,0};

    for (int k0 = 0; k0 < DFF; k0 += 64) {
        __syncthreads();
        #pragma unroll
        for (int j = 0; j < 4; ++j) {
            ASYNC16(ap[j] + k0, lA + j * 2048);
            ASYNC16(bp[j] + k0, lB + j * 2048);
        }
        __syncthreads();
        #pragma unroll
        for (int ksoff = 0; ksoff < 8; ksoff += 4) {
            bf16x8 a[4], b[4];
            #pragma unroll
            for (int i = 0; i < 4; ++i) {
                int m = wr + i * 16 + col;
                a[i] = *(const bf16x8*)&As[m * 64 + ((quad + ksoff) ^ (m & 7)) * 8];
            }
            #pragma unroll
            for (int n = 0; n < 4; ++n) {
                int nb = wc + n * 16 + col;
                b[n] = *(const bf16x8*)&Bs[nb * 64 + ((quad + ksoff) ^ (nb & 7)) * 8];
            }
            #pragma unroll
            for (int i = 0; i < 4; ++i)
                #pragma unroll
                for (int n = 0; n < 4; ++n)
                    acc[i][n] = __builtin_amdgcn_mfma_f32_16x16x32_bf16(a[i], b[n], acc[i][n], 0, 0, 0);
        }
    }
    #pragma unroll
    for (int i = 0; i < 4; ++i) {
        #pragma unroll
        for (int r = 0; r < 4; ++r) {
            int pos = mt * 128 + wr + i * 16 + quad * 4 + r;
            if (pos >= ne) continue;
            unsigned short* er = eo + (size_t)(base + pos) * DM + dt * 128 + wc + col;
            #pragma unroll
            for (int n = 0; n < 4; ++n)
                er[n * 16] = f2bf(acc[i][n][r]);
        }
    }
}

// ---------------- combine: out[t] = w1*eo[row1] + w2*eo[row2] ----------------
__global__ __launch_bounds__(256) void combine_kernel(
    const unsigned short* __restrict__ eo, const float2* __restrict__ topw,
    const int2* __restrict__ cidx, float* __restrict__ out)
{
    int idx = blockIdx.x * 256 + threadIdx.x;
    int t = idx >> 7;
    int c = (idx & 127) << 3;
    float2 w = topw[t];
    int2 rr = cidx[t];
    const unsigned short* p0 = eo + (size_t)rr.x * DM + c;
    const unsigned short* p1 = eo + (size_t)rr.y * DM + c;
    ushort4 a0 = *(const ushort4*)p0;
    ushort4 a1 = *(const ushort4*)(p0 + 4);
    ushort4 b0 = *(const ushort4*)p1;
    ushort4 b1 = *(const ushort4*)(p1 + 4);
    float* orow = out + (size_t)t * DM + c;
    float4 o0, o1;
    o0.x = w.x * bf2f(a0.x) + w.y * bf2f(b0.x);
    o0.y = w.x * bf2f(a0.y) + w.y * bf2f(b0.y);
    o0.z = w.x * bf2f(a0.z) + w.y * bf2f(b0.z);
    o0.w = w.x * bf2f(a0.w) + w.y * bf2f(b0.w);
    o1.x = w.x * bf2f(a1.x) + w.y * bf2f(b1.x);
    o1.y = w.x * bf2f(a1.y) + w.y * bf2f(b1.y);
    o1.z = w.x * bf2f(a1.z) + w.y * bf2f(b1.z);
    o1.w = w.x * bf2f(a1.w) + w.y * bf2f(b1.w);
    *(float4*)orow = o0;
    *(float4*)(orow + 4) = o1;
}

extern "C" void kernel_launch(void* const* d_in, const int* in_sizes, int n_in,
                              void* d_out, int out_size, void* d_ws, size_t ws_size,
                              hipStream_t stream) {
    const float* x      = (const float*)d_in[0];
    const float* gate_w = (const float*)d_in[1];
    const float* w_gate = (const float*)d_in[2];
    const float* w_up   = (const float*)d_in[3];
    const float* w_down = (const float*)d_in[4];
    float* out = (float*)d_out;

    char* p = (char*)d_ws;
    unsigned short* xb   = (unsigned short*)p; p += (size_t)T_TOK * DM * 2;
    unsigned short* wgb  = (unsigned short*)p; p += (size_t)NE * DFF * DM * 2;
    unsigned short* wub  = (unsigned short*)p; p += (size_t)NE * DFF * DM * 2;
    unsigned short* wdb  = (unsigned short*)p; p += (size_t)NE * DM * DFF * 2;
    unsigned short* Hbuf = (unsigned short*)p; p += (size_t)TOTS * DFF * 2;
    int*   elist = (int*)p;   p += (size_t)TOTS * 4;
    int*   ecnt  = (int*)p;   p += NE * 4;
    int*   ebaseg= (int*)p;   p += NE * 4;
    int*   topi  = (int*)p;   p += (size_t)T_TOK * 4;
    float2* topw = (float2*)p; p += (size_t)T_TOK * 8;
    int2*  cidx  = (int2*)p;  p += (size_t)T_TOK * 8;
    float* psum_part = (float*)p; p += (size_t)R1_BLK * NE * 4;
    // eo aliases wgb+wub (dead after gemm1): [TOTS][DM] bf16 = 33.5 MB
    unsigned short* eo = wgb;

    pre_kernel<<<R1_BLK + CVT_BLK, 256, 0, stream>>>(
        x, gate_w, w_gate, w_up, w_down, wgb, wub, wdb,
        xb, topi, topw, psum_part);
    scatfin_kernel<<<NE, 256, 0, stream>>>(topi, psum_part, elist, cidx, ecnt, ebaseg,
                                           out + (size_t)T_TOK * DM);
    gemm1_kernel<<<dim3(DFF / 64, TOTS / 128, NE), 256, 0, stream>>>(
        xb, wgb, wub, elist, ecnt, ebaseg, Hbuf);
    gemm2_kernel<<<dim3(DM / 128, TOTS / 128, NE), 256, 0, stream>>>(
        Hbuf, wdb, ecnt, ebaseg, eo);
    combine_kernel<<<T_TOK * DM / 8 / 256, 256, 0, stream>>>(eo, topw, cidx, out);
}